// Round 5
// baseline (458.970 us; speedup 1.0000x reference)
//
#include <hip/hip_runtime.h>
#include <hip/hip_bf16.h>
#include <cstddef>

// ---------------------------------------------------------------------------
// 3-layer MPNN, N=50000, E=800000, D=128, OUT=32.
// R5: g = Sigma_in w*h[src] (gather);  h' = tanh([g|h]@[Wm;Wu]^T+bu) (K=256
// MFMA GEMM, tanh epilogue);  out = h3@Wout^T+bout.
// CSR entry packed to 4B: (src:u16 | w:bf16<<16)  [N < 65536].
// Single-block 1024-thread scan. Aggregate: 1 wave/node, 4 edge-slots x
// 16 feat-lanes x 16B for 4 gathers in flight + shfl_xor reduction.
// ---------------------------------------------------------------------------

typedef __attribute__((ext_vector_type(8))) short short8;
typedef __attribute__((ext_vector_type(4))) float f32x4;
typedef unsigned short ushort_t;
typedef unsigned int uint_t;

__device__ inline ushort_t f2bf(float f) {  // round-to-nearest-even
    uint_t u = __float_as_uint(f);
    uint_t r = u + 0x7FFFu + ((u >> 16) & 1u);
    return (ushort_t)(r >> 16);
}
__device__ inline float bf_lo(uint_t u) { return __uint_as_float(u << 16); }
__device__ inline float bf_hi(uint_t u) { return __uint_as_float(u & 0xFFFF0000u); }
__device__ inline uint_t packbf(float a, float b) {
    return (uint_t)f2bf(a) | ((uint_t)f2bf(b) << 16);
}

// vectorized edge fetch. flag=1 -> int32 [2][E]; flag=0 -> int64 [2][E]
__device__ inline int get_dst(const int* __restrict__ ei, int e, int E, int f) {
    if (f) return ei[E + e];
    return ((const int2*)ei)[(size_t)E + e].x;
}
__device__ inline int get_src(const int* __restrict__ ei, int e, int E, int f) {
    if (f) return ei[e];
    return ((const int2*)ei)[e].x;
}

// ---------------------------------------------------------------------------
// Fused setup: zero deg | detect idx layout | bf16 Wcat=[Wm|Wu] + Wout |
// x -> bf16.
// ---------------------------------------------------------------------------
struct SetupArgs {
    const float* Wm0; const float* Wu0;
    const float* Wm1; const float* Wu1;
    const float* Wm2; const float* Wu2;
    const float* Wout;
    const float* x; const int* ei;
    ushort_t* wcat;    // 3 * 128*256
    ushort_t* woutb;   // 32*128
    ushort_t* xb;      // N*128
    int* deg; int* flag;
    int N, E;
    int ZB, WB, XB;
};
__global__ __launch_bounds__(256) void setup_kernel(SetupArgs a) {
    int bx = blockIdx.x, t = threadIdx.x;
    if (bx < a.ZB) {
        int i = bx * 256 + t;
        if (i < a.N) a.deg[i] = 0;
        return;
    }
    bx -= a.ZB;
    if (bx == 0) {
        __shared__ int any;
        if (t == 0) any = 0;
        __syncthreads();
        int n = a.E < 2048 ? a.E : 2048;
        for (int i = t; i < n; i += 256)
            if (a.ei[2 * i + 1] != 0) any = 1;
        __syncthreads();
        if (t == 0) a.flag[0] = any;
        return;
    }
    bx -= 1;
    if (bx < a.WB) {
        int i = bx * 256 + t;
        if (i < 3 * 32768) {
            int l = i >> 15, rem = i & 32767, r = rem >> 8, k = rem & 255;
            const float* Wm = l == 0 ? a.Wm0 : (l == 1 ? a.Wm1 : a.Wm2);
            const float* Wu = l == 0 ? a.Wu0 : (l == 1 ? a.Wu1 : a.Wu2);
            float v = k < 128 ? Wm[r * 128 + k] : Wu[r * 128 + (k - 128)];
            a.wcat[(size_t)l * 32768 + r * 256 + k] = f2bf(v);
        } else if (i < 3 * 32768 + 4096) {
            int j = i - 3 * 32768;
            a.woutb[j] = f2bf(a.Wout[j]);
        }
        return;
    }
    bx -= a.WB;
    {
        int j = bx * 256 + t;
        if (j < a.N * 32) {
            float4 v = *(const float4*)(a.x + (size_t)j * 4);
            uint2 o;
            o.x = packbf(v.x, v.y);
            o.y = packbf(v.z, v.w);
            *(uint2*)(a.xb + (size_t)j * 4) = o;
        }
    }
}

// ---- CSR build ----
__global__ __launch_bounds__(256) void hist_kernel(
    const int* __restrict__ ei, int* __restrict__ deg, int E,
    const int* __restrict__ flag) {
    int e = blockIdx.x * 256 + threadIdx.x;
    if (e >= E) return;
    atomicAdd(&deg[get_dst(ei, e, E, flag[0])], 1);
}

// single-block exclusive scan, 1024 threads, chunk-per-thread + LDS scan
__global__ __launch_bounds__(1024) void scan_one(
    const int* __restrict__ deg, int* __restrict__ rowptr, int N) {
    __shared__ int sm[1024];
    const int t = threadIdx.x;
    const int C = (N + 1023) / 1024;
    int beg = t * C;
    int end = beg + C < N ? beg + C : N;
    int s = 0;
    for (int i = beg; i < end; ++i) s += deg[i];
    sm[t] = s;
    __syncthreads();
    for (int o = 1; o < 1024; o <<= 1) {
        int v = t >= o ? sm[t - o] : 0;
        __syncthreads();
        sm[t] += v;
        __syncthreads();
    }
    int run = t ? sm[t - 1] : 0;
    for (int i = beg; i < end; ++i) {
        rowptr[i] = run;
        run += deg[i];
    }
}

// bucket-fill; one packed 4B scattered write per edge. rowptr -> rowend.
__global__ __launch_bounds__(256) void fill_kernel(
    const int* __restrict__ ei, const float* __restrict__ ew,
    int* __restrict__ rowptr, uint_t* __restrict__ csr, int E,
    const int* __restrict__ flag) {
    int e = blockIdx.x * 256 + threadIdx.x;
    if (e >= E) return;
    int f = flag[0];
    int s = get_src(ei, e, E, f);
    int d = get_dst(ei, e, E, f);
    int pos = atomicAdd(&rowptr[d], 1);
    csr[pos] = (uint_t)s | ((uint_t)f2bf(ew[e]) << 16);
}

// ---------------------------------------------------------------------------
// Aggregate: g[d] = Sigma_{in(d)} w*h[src]. One 64-lane wave per node.
// lane = e_slot(0..3)*16 + f16(0..15); lane loads 16B (8 bf16 feats).
// 4 row-gathers in flight per iteration; shfl_xor(16,32) reduce at end.
// ---------------------------------------------------------------------------
__global__ __launch_bounds__(256) void aggregate_g(
    const uint_t* __restrict__ csr, const int* __restrict__ rowend,
    const int* __restrict__ deg, const ushort_t* __restrict__ h,
    ushort_t* __restrict__ g, int N) {
    int node = (blockIdx.x * 256 + threadIdx.x) >> 6;
    if (node >= N) return;
    int lane = threadIdx.x & 63;
    int e_slot = lane >> 4, f16 = lane & 15;
    int end = rowend[node];
    int beg = end - deg[node];
    float s0 = 0.f, s1 = 0.f, s2 = 0.f, s3 = 0.f;
    float s4 = 0.f, s5 = 0.f, s6 = 0.f, s7 = 0.f;
    for (int j = beg + e_slot; j < end; j += 4) {
        uint_t p = csr[j];
        float w = bf_hi(p);
        uint4 v = *(const uint4*)(h + (size_t)(p & 0xFFFFu) * 128 + f16 * 8);
        s0 += w * bf_lo(v.x); s1 += w * bf_hi(v.x);
        s2 += w * bf_lo(v.y); s3 += w * bf_hi(v.y);
        s4 += w * bf_lo(v.z); s5 += w * bf_hi(v.z);
        s6 += w * bf_lo(v.w); s7 += w * bf_hi(v.w);
    }
    // reduce across the 4 edge-slots (lane bits 4 and 5)
    s0 += __shfl_xor(s0, 16, 64); s1 += __shfl_xor(s1, 16, 64);
    s2 += __shfl_xor(s2, 16, 64); s3 += __shfl_xor(s3, 16, 64);
    s4 += __shfl_xor(s4, 16, 64); s5 += __shfl_xor(s5, 16, 64);
    s6 += __shfl_xor(s6, 16, 64); s7 += __shfl_xor(s7, 16, 64);
    s0 += __shfl_xor(s0, 32, 64); s1 += __shfl_xor(s1, 32, 64);
    s2 += __shfl_xor(s2, 32, 64); s3 += __shfl_xor(s3, 32, 64);
    s4 += __shfl_xor(s4, 32, 64); s5 += __shfl_xor(s5, 32, 64);
    s6 += __shfl_xor(s6, 32, 64); s7 += __shfl_xor(s7, 32, 64);
    if (e_slot == 0) {
        uint4 o;
        o.x = packbf(s0, s1);
        o.y = packbf(s2, s3);
        o.z = packbf(s4, s5);
        o.w = packbf(s6, s7);
        *(uint4*)(g + (size_t)node * 128 + f16 * 8) = o;
    }
}

// ---------------------------------------------------------------------------
// Fused layer GEMM: Hout[N,128] = tanh([G|H][N,256] @ Wcat[128,256]^T + bu)
// BM=64, BN=128; LDS chunk layout (lane-contiguous 16B, conflict-free).
// ---------------------------------------------------------------------------
__global__ __launch_bounds__(256) void fused_gemm(
    const ushort_t* __restrict__ G, const ushort_t* __restrict__ H,
    const ushort_t* __restrict__ Wcat, const float* __restrict__ bias,
    ushort_t* __restrict__ Hout, int N) {
    __shared__ short As[64 * 128];    // 16 KB
    __shared__ short Ws[128 * 128];   // 32 KB
    const int tid = threadIdx.x;
    const int row0 = blockIdx.x * 64;
    const int wv = tid >> 6, lane = tid & 63;
    const int rt = wv;

    f32x4 acc[8];
#pragma unroll
    for (int ct = 0; ct < 8; ++ct) acc[ct] = (f32x4){0.f, 0.f, 0.f, 0.f};

#pragma unroll
    for (int chunk = 0; chunk < 2; ++chunk) {
        const ushort_t* A = chunk ? H : G;
        const int kco = chunk * 128;
        if (chunk) __syncthreads();
#pragma unroll
        for (int it = 0; it < 4; ++it) {
            int c = tid + 256 * it;
            int mm = c & 15, q = (c >> 4) & 3, ks = (c >> 6) & 3, rtile = c >> 8;
            int gr = row0 + rtile * 16 + mm;
            short8 v = {0, 0, 0, 0, 0, 0, 0, 0};
            if (gr < N) v = *(const short8*)(A + (size_t)gr * 128 + ks * 32 + q * 8);
            *(short8*)&As[c * 8] = v;
        }
#pragma unroll
        for (int it = 0; it < 8; ++it) {
            int c = tid + 256 * it;
            int mm = c & 15, q = (c >> 4) & 3, ks = (c >> 6) & 3, ct = c >> 8;
            *(short8*)&Ws[c * 8] =
                *(const short8*)(Wcat + (size_t)(ct * 16 + mm) * 256 + kco + ks * 32 + q * 8);
        }
        __syncthreads();
#pragma unroll
        for (int ks = 0; ks < 4; ++ks) {
            short8 a = *(const short8*)&As[((rt * 4 + ks) * 64 + lane) * 8];
#pragma unroll
            for (int ct = 0; ct < 8; ++ct) {
                short8 b = *(const short8*)&Ws[((ct * 4 + ks) * 64 + lane) * 8];
                acc[ct] = __builtin_amdgcn_mfma_f32_16x16x32_bf16(a, b, acc[ct], 0, 0, 0);
            }
        }
    }
    const int colL = lane & 15, rq = lane >> 4;
#pragma unroll
    for (int ct = 0; ct < 8; ++ct) {
        int col = ct * 16 + colL;
        float bv = bias[col];
#pragma unroll
        for (int reg = 0; reg < 4; ++reg) {
            int gr = row0 + rt * 16 + rq * 4 + reg;
            if (gr >= N) continue;
            Hout[(size_t)gr * 128 + col] = f2bf(tanhf(acc[ct][reg] + bv));
        }
    }
}

// out[N,32] = H_bf16[N,128] @ Wout^T + bout (fp32). BM=128.
__global__ __launch_bounds__(256) void mfma_gemm_out(
    const ushort_t* __restrict__ H, const ushort_t* __restrict__ Wb,
    const float* __restrict__ bias, float* __restrict__ C, int N) {
    __shared__ short As[128 * 128];  // 32 KB
    __shared__ short Ws[32 * 128];   // 8 KB
    const int tid = threadIdx.x;
    const int row0 = blockIdx.x * 128;
#pragma unroll
    for (int it = 0; it < 8; ++it) {
        int c = tid + 256 * it;
        int mm = c & 15, q = (c >> 4) & 3, ks = (c >> 6) & 3, rt = c >> 8;
        int gr = row0 + rt * 16 + mm;
        short8 v = {0, 0, 0, 0, 0, 0, 0, 0};
        if (gr < N) v = *(const short8*)(H + (size_t)gr * 128 + ks * 32 + q * 8);
        *(short8*)&As[c * 8] = v;
    }
#pragma unroll
    for (int it = 0; it < 2; ++it) {
        int c = tid + 256 * it;
        int mm = c & 15, q = (c >> 4) & 3, ks = (c >> 6) & 3, ct = c >> 8;
        *(short8*)&Ws[c * 8] =
            *(const short8*)(Wb + (ct * 16 + mm) * 128 + ks * 32 + q * 8);
    }
    __syncthreads();
    const int wv = tid >> 6, lane = tid & 63;
    const int rt0 = wv * 2;
    f32x4 acc[2][2];
#pragma unroll
    for (int r = 0; r < 2; ++r)
#pragma unroll
        for (int c = 0; c < 2; ++c) acc[r][c] = (f32x4){0.f, 0.f, 0.f, 0.f};
#pragma unroll
    for (int ks = 0; ks < 4; ++ks) {
        short8 a0 = *(const short8*)&As[(((rt0 + 0) * 4 + ks) * 64 + lane) * 8];
        short8 a1 = *(const short8*)&As[(((rt0 + 1) * 4 + ks) * 64 + lane) * 8];
#pragma unroll
        for (int ct = 0; ct < 2; ++ct) {
            short8 b = *(const short8*)&Ws[((ct * 4 + ks) * 64 + lane) * 8];
            acc[0][ct] = __builtin_amdgcn_mfma_f32_16x16x32_bf16(a0, b, acc[0][ct], 0, 0, 0);
            acc[1][ct] = __builtin_amdgcn_mfma_f32_16x16x32_bf16(a1, b, acc[1][ct], 0, 0, 0);
        }
    }
    const int colL = lane & 15, rq = lane >> 4;
#pragma unroll
    for (int r = 0; r < 2; ++r)
#pragma unroll
        for (int ct = 0; ct < 2; ++ct) {
            int col = ct * 16 + colL;
            float bv = bias[col];
#pragma unroll
            for (int reg = 0; reg < 4; ++reg) {
                int gr = row0 + (rt0 + r) * 16 + rq * 4 + reg;
                if (gr < N) C[(size_t)gr * 32 + col] = acc[r][ct][reg] + bv;
            }
        }
}

extern "C" void kernel_launch(void* const* d_in, const int* in_sizes, int n_in,
                              void* d_out, int out_size, void* d_ws, size_t ws_size,
                              hipStream_t stream) {
    const float* x   = (const float*)d_in[0];
    const int* ei    = (const int*)d_in[1];
    const float* ew  = (const float*)d_in[2];
    const float* Wm[3] = {(const float*)d_in[3], (const float*)d_in[6], (const float*)d_in[9]};
    const float* Wu[3] = {(const float*)d_in[4], (const float*)d_in[7], (const float*)d_in[10]};
    const float* bu[3] = {(const float*)d_in[5], (const float*)d_in[8], (const float*)d_in[11]};
    const float* Wout = (const float*)d_in[12];
    const float* bout = (const float*)d_in[13];
    float* out = (float*)d_out;

    const int N = in_sizes[0] / 128;
    const int E = in_sizes[2];
    const size_t NPAD = 50048;

    ushort_t* xb    = (ushort_t*)d_ws;              // [N,128] bf16
    ushort_t* hA    = xb + NPAD * 128;
    ushort_t* hB    = hA + NPAD * 128;
    ushort_t* gbuf  = hB + NPAD * 128;
    ushort_t* wcat  = gbuf + NPAD * 128;            // 3*128*256 bf16
    ushort_t* woutb = wcat + 3 * 32768;             // 32*128 bf16
    int* flag       = (int*)(woutb + 4096);
    int* deg        = flag + 1;
    int* rowptr     = deg + N;
    uint_t* csr     = (uint_t*)(rowptr + N);        // E packed entries
    (void)ws_size;

    const int ZB = (N + 255) / 256;
    const int WB = (3 * 32768 + 4096 + 255) / 256;
    const int XB = (N * 32 + 255) / 256;
    const int gE1 = (E + 255) / 256;
    const int gG = (N + 63) / 64;
    const int gA = (N + 3) / 4;        // 1 wave/node, 4 nodes/block
    const int gO = (N + 127) / 128;

    SetupArgs sa;
    sa.Wm0 = Wm[0]; sa.Wu0 = Wu[0];
    sa.Wm1 = Wm[1]; sa.Wu1 = Wu[1];
    sa.Wm2 = Wm[2]; sa.Wu2 = Wu[2];
    sa.Wout = Wout; sa.x = x; sa.ei = ei;
    sa.wcat = wcat; sa.woutb = woutb; sa.xb = xb;
    sa.deg = deg; sa.flag = flag;
    sa.N = N; sa.E = E; sa.ZB = ZB; sa.WB = WB; sa.XB = XB;
    setup_kernel<<<ZB + 1 + WB + XB, 256, 0, stream>>>(sa);

    hist_kernel<<<gE1, 256, 0, stream>>>(ei, deg, E, flag);
    scan_one<<<1, 1024, 0, stream>>>(deg, rowptr, N);
    fill_kernel<<<gE1, 256, 0, stream>>>(ei, ew, rowptr, csr, E, flag);

    const ushort_t* hin[3] = {xb, hA, hB};
    ushort_t* hout[3] = {hA, hB, hA};
    for (int l = 0; l < 3; ++l) {
        aggregate_g<<<gA, 256, 0, stream>>>(csr, rowptr, deg, hin[l], gbuf, N);
        fused_gemm<<<gG, 256, 0, stream>>>(gbuf, hin[l], wcat + (size_t)l * 32768,
                                           bu[l], hout[l], N);
    }
    mfma_gemm_out<<<gO, 256, 0, stream>>>(hA, woutb, bout, out, N);
}

// Round 6
// 389.387 us; speedup vs baseline: 1.1787x; 1.1787x over previous
//
#include <hip/hip_runtime.h>
#include <hip/hip_bf16.h>
#include <cstddef>

// ---------------------------------------------------------------------------
// 3-layer MPNN, N=50000, E=800000, D=128, OUT=32.
// R6: R5 structure with the scan reverted to the proven 3-phase multi-block
// version (single-block scans have a ~80us latency floor on MI355X —
// measured R2: 86us @196 elem/thread, R5: 76us @49 elem/thread).
//   g = Sigma_in w*h[src] (gather);  h' = tanh([g|h]@[Wm;Wu]^T+bu) (K=256
//   MFMA GEMM, tanh epilogue);  out = h3@Wout^T+bout.
// CSR entry packed to 4B: (src:u16 | w:bf16<<16)  [N < 65536].
// ---------------------------------------------------------------------------

typedef __attribute__((ext_vector_type(8))) short short8;
typedef __attribute__((ext_vector_type(4))) float f32x4;
typedef unsigned short ushort_t;
typedef unsigned int uint_t;

__device__ inline ushort_t f2bf(float f) {  // round-to-nearest-even
    uint_t u = __float_as_uint(f);
    uint_t r = u + 0x7FFFu + ((u >> 16) & 1u);
    return (ushort_t)(r >> 16);
}
__device__ inline float bf_lo(uint_t u) { return __uint_as_float(u << 16); }
__device__ inline float bf_hi(uint_t u) { return __uint_as_float(u & 0xFFFF0000u); }
__device__ inline uint_t packbf(float a, float b) {
    return (uint_t)f2bf(a) | ((uint_t)f2bf(b) << 16);
}

// vectorized edge fetch. flag=1 -> int32 [2][E]; flag=0 -> int64 [2][E]
__device__ inline int get_dst(const int* __restrict__ ei, int e, int E, int f) {
    if (f) return ei[E + e];
    return ((const int2*)ei)[(size_t)E + e].x;
}
__device__ inline int get_src(const int* __restrict__ ei, int e, int E, int f) {
    if (f) return ei[e];
    return ((const int2*)ei)[e].x;
}

// ---------------------------------------------------------------------------
// Fused setup: zero deg | detect idx layout | bf16 Wcat=[Wm|Wu] + Wout |
// x -> bf16.
// ---------------------------------------------------------------------------
struct SetupArgs {
    const float* Wm0; const float* Wu0;
    const float* Wm1; const float* Wu1;
    const float* Wm2; const float* Wu2;
    const float* Wout;
    const float* x; const int* ei;
    ushort_t* wcat;    // 3 * 128*256
    ushort_t* woutb;   // 32*128
    ushort_t* xb;      // N*128
    int* deg; int* flag;
    int N, E;
    int ZB, WB, XB;
};
__global__ __launch_bounds__(256) void setup_kernel(SetupArgs a) {
    int bx = blockIdx.x, t = threadIdx.x;
    if (bx < a.ZB) {
        int i = bx * 256 + t;
        if (i < a.N) a.deg[i] = 0;
        return;
    }
    bx -= a.ZB;
    if (bx == 0) {
        __shared__ int any;
        if (t == 0) any = 0;
        __syncthreads();
        int n = a.E < 2048 ? a.E : 2048;
        for (int i = t; i < n; i += 256)
            if (a.ei[2 * i + 1] != 0) any = 1;
        __syncthreads();
        if (t == 0) a.flag[0] = any;
        return;
    }
    bx -= 1;
    if (bx < a.WB) {
        int i = bx * 256 + t;
        if (i < 3 * 32768) {
            int l = i >> 15, rem = i & 32767, r = rem >> 8, k = rem & 255;
            const float* Wm = l == 0 ? a.Wm0 : (l == 1 ? a.Wm1 : a.Wm2);
            const float* Wu = l == 0 ? a.Wu0 : (l == 1 ? a.Wu1 : a.Wu2);
            float v = k < 128 ? Wm[r * 128 + k] : Wu[r * 128 + (k - 128)];
            a.wcat[(size_t)l * 32768 + r * 256 + k] = f2bf(v);
        } else if (i < 3 * 32768 + 4096) {
            int j = i - 3 * 32768;
            a.woutb[j] = f2bf(a.Wout[j]);
        }
        return;
    }
    bx -= a.WB;
    {
        int j = bx * 256 + t;
        if (j < a.N * 32) {
            float4 v = *(const float4*)(a.x + (size_t)j * 4);
            uint2 o;
            o.x = packbf(v.x, v.y);
            o.y = packbf(v.z, v.w);
            *(uint2*)(a.xb + (size_t)j * 4) = o;
        }
    }
}

// ---- CSR build ----
__global__ __launch_bounds__(256) void hist_kernel(
    const int* __restrict__ ei, int* __restrict__ deg, int E,
    const int* __restrict__ flag) {
    int e = blockIdx.x * 256 + threadIdx.x;
    if (e >= E) return;
    atomicAdd(&deg[get_dst(ei, e, E, flag[0])], 1);
}

// 3-phase exclusive scan of deg[N] -> rowptr[N]  (multi-block; single-block
// serial scans measured at a ~80us latency floor on this part)
__global__ __launch_bounds__(256) void scan_partial(
    const int* __restrict__ deg, int* __restrict__ bsum, int N) {
    __shared__ int sm[256];
    int i = blockIdx.x * 256 + threadIdx.x;
    sm[threadIdx.x] = i < N ? deg[i] : 0;
    __syncthreads();
    for (int o = 128; o > 0; o >>= 1) {
        if (threadIdx.x < o) sm[threadIdx.x] += sm[threadIdx.x + o];
        __syncthreads();
    }
    if (threadIdx.x == 0) bsum[blockIdx.x] = sm[0];
}
__global__ __launch_bounds__(256) void scan_bsum(
    const int* __restrict__ bsum, int* __restrict__ boff, int PB) {
    __shared__ int sm[256];
    int t = threadIdx.x;
    sm[t] = t < PB ? bsum[t] : 0;
    __syncthreads();
    for (int o = 1; o < 256; o <<= 1) {
        int v = t >= o ? sm[t - o] : 0;
        __syncthreads();
        sm[t] += v;
        __syncthreads();
    }
    if (t < PB) boff[t] = t ? sm[t - 1] : 0;
}
__global__ __launch_bounds__(256) void scan_write(
    const int* __restrict__ deg, const int* __restrict__ boff,
    int* __restrict__ rowptr, int N) {
    __shared__ int sm[256];
    int t = threadIdx.x;
    int i = blockIdx.x * 256 + t;
    int v = i < N ? deg[i] : 0;
    sm[t] = v;
    __syncthreads();
    for (int o = 1; o < 256; o <<= 1) {
        int u = t >= o ? sm[t - o] : 0;
        __syncthreads();
        sm[t] += u;
        __syncthreads();
    }
    if (i < N) rowptr[i] = boff[blockIdx.x] + sm[t] - v;
}

// bucket-fill; one packed 4B scattered write per edge. rowptr -> rowend.
__global__ __launch_bounds__(256) void fill_kernel(
    const int* __restrict__ ei, const float* __restrict__ ew,
    int* __restrict__ rowptr, uint_t* __restrict__ csr, int E,
    const int* __restrict__ flag) {
    int e = blockIdx.x * 256 + threadIdx.x;
    if (e >= E) return;
    int f = flag[0];
    int s = get_src(ei, e, E, f);
    int d = get_dst(ei, e, E, f);
    int pos = atomicAdd(&rowptr[d], 1);
    csr[pos] = (uint_t)s | ((uint_t)f2bf(ew[e]) << 16);
}

// ---------------------------------------------------------------------------
// Aggregate: g[d] = Sigma_{in(d)} w*h[src]. One 64-lane wave per node.
// lane = e_slot(0..3)*16 + f16(0..15); lane loads 16B (8 bf16 feats).
// 4 row-gathers in flight per iteration; shfl_xor(16,32) reduce at end.
// ---------------------------------------------------------------------------
__global__ __launch_bounds__(256) void aggregate_g(
    const uint_t* __restrict__ csr, const int* __restrict__ rowend,
    const int* __restrict__ deg, const ushort_t* __restrict__ h,
    ushort_t* __restrict__ g, int N) {
    int node = (blockIdx.x * 256 + threadIdx.x) >> 6;
    if (node >= N) return;
    int lane = threadIdx.x & 63;
    int e_slot = lane >> 4, f16 = lane & 15;
    int end = rowend[node];
    int beg = end - deg[node];
    float s0 = 0.f, s1 = 0.f, s2 = 0.f, s3 = 0.f;
    float s4 = 0.f, s5 = 0.f, s6 = 0.f, s7 = 0.f;
    for (int j = beg + e_slot; j < end; j += 4) {
        uint_t p = csr[j];
        float w = bf_hi(p);
        uint4 v = *(const uint4*)(h + (size_t)(p & 0xFFFFu) * 128 + f16 * 8);
        s0 += w * bf_lo(v.x); s1 += w * bf_hi(v.x);
        s2 += w * bf_lo(v.y); s3 += w * bf_hi(v.y);
        s4 += w * bf_lo(v.z); s5 += w * bf_hi(v.z);
        s6 += w * bf_lo(v.w); s7 += w * bf_hi(v.w);
    }
    // reduce across the 4 edge-slots (lane bits 4 and 5)
    s0 += __shfl_xor(s0, 16, 64); s1 += __shfl_xor(s1, 16, 64);
    s2 += __shfl_xor(s2, 16, 64); s3 += __shfl_xor(s3, 16, 64);
    s4 += __shfl_xor(s4, 16, 64); s5 += __shfl_xor(s5, 16, 64);
    s6 += __shfl_xor(s6, 16, 64); s7 += __shfl_xor(s7, 16, 64);
    s0 += __shfl_xor(s0, 32, 64); s1 += __shfl_xor(s1, 32, 64);
    s2 += __shfl_xor(s2, 32, 64); s3 += __shfl_xor(s3, 32, 64);
    s4 += __shfl_xor(s4, 32, 64); s5 += __shfl_xor(s5, 32, 64);
    s6 += __shfl_xor(s6, 32, 64); s7 += __shfl_xor(s7, 32, 64);
    if (e_slot == 0) {
        uint4 o;
        o.x = packbf(s0, s1);
        o.y = packbf(s2, s3);
        o.z = packbf(s4, s5);
        o.w = packbf(s6, s7);
        *(uint4*)(g + (size_t)node * 128 + f16 * 8) = o;
    }
}

// ---------------------------------------------------------------------------
// Fused layer GEMM: Hout[N,128] = tanh([G|H][N,256] @ Wcat[128,256]^T + bu)
// BM=64, BN=128; LDS chunk layout (lane-contiguous 16B, conflict-free).
// ---------------------------------------------------------------------------
__global__ __launch_bounds__(256) void fused_gemm(
    const ushort_t* __restrict__ G, const ushort_t* __restrict__ H,
    const ushort_t* __restrict__ Wcat, const float* __restrict__ bias,
    ushort_t* __restrict__ Hout, int N) {
    __shared__ short As[64 * 128];    // 16 KB
    __shared__ short Ws[128 * 128];   // 32 KB
    const int tid = threadIdx.x;
    const int row0 = blockIdx.x * 64;
    const int wv = tid >> 6, lane = tid & 63;
    const int rt = wv;

    f32x4 acc[8];
#pragma unroll
    for (int ct = 0; ct < 8; ++ct) acc[ct] = (f32x4){0.f, 0.f, 0.f, 0.f};

#pragma unroll
    for (int chunk = 0; chunk < 2; ++chunk) {
        const ushort_t* A = chunk ? H : G;
        const int kco = chunk * 128;
        if (chunk) __syncthreads();
#pragma unroll
        for (int it = 0; it < 4; ++it) {
            int c = tid + 256 * it;
            int mm = c & 15, q = (c >> 4) & 3, ks = (c >> 6) & 3, rtile = c >> 8;
            int gr = row0 + rtile * 16 + mm;
            short8 v = {0, 0, 0, 0, 0, 0, 0, 0};
            if (gr < N) v = *(const short8*)(A + (size_t)gr * 128 + ks * 32 + q * 8);
            *(short8*)&As[c * 8] = v;
        }
#pragma unroll
        for (int it = 0; it < 8; ++it) {
            int c = tid + 256 * it;
            int mm = c & 15, q = (c >> 4) & 3, ks = (c >> 6) & 3, ct = c >> 8;
            *(short8*)&Ws[c * 8] =
                *(const short8*)(Wcat + (size_t)(ct * 16 + mm) * 256 + kco + ks * 32 + q * 8);
        }
        __syncthreads();
#pragma unroll
        for (int ks = 0; ks < 4; ++ks) {
            short8 a = *(const short8*)&As[((rt * 4 + ks) * 64 + lane) * 8];
#pragma unroll
            for (int ct = 0; ct < 8; ++ct) {
                short8 b = *(const short8*)&Ws[((ct * 4 + ks) * 64 + lane) * 8];
                acc[ct] = __builtin_amdgcn_mfma_f32_16x16x32_bf16(a, b, acc[ct], 0, 0, 0);
            }
        }
    }
    const int colL = lane & 15, rq = lane >> 4;
#pragma unroll
    for (int ct = 0; ct < 8; ++ct) {
        int col = ct * 16 + colL;
        float bv = bias[col];
#pragma unroll
        for (int reg = 0; reg < 4; ++reg) {
            int gr = row0 + rt * 16 + rq * 4 + reg;
            if (gr >= N) continue;
            Hout[(size_t)gr * 128 + col] = f2bf(tanhf(acc[ct][reg] + bv));
        }
    }
}

// out[N,32] = H_bf16[N,128] @ Wout^T + bout (fp32). BM=128.
__global__ __launch_bounds__(256) void mfma_gemm_out(
    const ushort_t* __restrict__ H, const ushort_t* __restrict__ Wb,
    const float* __restrict__ bias, float* __restrict__ C, int N) {
    __shared__ short As[128 * 128];  // 32 KB
    __shared__ short Ws[32 * 128];   // 8 KB
    const int tid = threadIdx.x;
    const int row0 = blockIdx.x * 128;
#pragma unroll
    for (int it = 0; it < 8; ++it) {
        int c = tid + 256 * it;
        int mm = c & 15, q = (c >> 4) & 3, ks = (c >> 6) & 3, rt = c >> 8;
        int gr = row0 + rt * 16 + mm;
        short8 v = {0, 0, 0, 0, 0, 0, 0, 0};
        if (gr < N) v = *(const short8*)(H + (size_t)gr * 128 + ks * 32 + q * 8);
        *(short8*)&As[c * 8] = v;
    }
#pragma unroll
    for (int it = 0; it < 2; ++it) {
        int c = tid + 256 * it;
        int mm = c & 15, q = (c >> 4) & 3, ks = (c >> 6) & 3, ct = c >> 8;
        *(short8*)&Ws[c * 8] =
            *(const short8*)(Wb + (ct * 16 + mm) * 128 + ks * 32 + q * 8);
    }
    __syncthreads();
    const int wv = tid >> 6, lane = tid & 63;
    const int rt0 = wv * 2;
    f32x4 acc[2][2];
#pragma unroll
    for (int r = 0; r < 2; ++r)
#pragma unroll
        for (int c = 0; c < 2; ++c) acc[r][c] = (f32x4){0.f, 0.f, 0.f, 0.f};
#pragma unroll
    for (int ks = 0; ks < 4; ++ks) {
        short8 a0 = *(const short8*)&As[(((rt0 + 0) * 4 + ks) * 64 + lane) * 8];
        short8 a1 = *(const short8*)&As[(((rt0 + 1) * 4 + ks) * 64 + lane) * 8];
#pragma unroll
        for (int ct = 0; ct < 2; ++ct) {
            short8 b = *(const short8*)&Ws[((ct * 4 + ks) * 64 + lane) * 8];
            acc[0][ct] = __builtin_amdgcn_mfma_f32_16x16x32_bf16(a0, b, acc[0][ct], 0, 0, 0);
            acc[1][ct] = __builtin_amdgcn_mfma_f32_16x16x32_bf16(a1, b, acc[1][ct], 0, 0, 0);
        }
    }
    const int colL = lane & 15, rq = lane >> 4;
#pragma unroll
    for (int r = 0; r < 2; ++r)
#pragma unroll
        for (int ct = 0; ct < 2; ++ct) {
            int col = ct * 16 + colL;
            float bv = bias[col];
#pragma unroll
            for (int reg = 0; reg < 4; ++reg) {
                int gr = row0 + (rt0 + r) * 16 + rq * 4 + reg;
                if (gr < N) C[(size_t)gr * 32 + col] = acc[r][ct][reg] + bv;
            }
        }
}

extern "C" void kernel_launch(void* const* d_in, const int* in_sizes, int n_in,
                              void* d_out, int out_size, void* d_ws, size_t ws_size,
                              hipStream_t stream) {
    const float* x   = (const float*)d_in[0];
    const int* ei    = (const int*)d_in[1];
    const float* ew  = (const float*)d_in[2];
    const float* Wm[3] = {(const float*)d_in[3], (const float*)d_in[6], (const float*)d_in[9]};
    const float* Wu[3] = {(const float*)d_in[4], (const float*)d_in[7], (const float*)d_in[10]};
    const float* bu[3] = {(const float*)d_in[5], (const float*)d_in[8], (const float*)d_in[11]};
    const float* Wout = (const float*)d_in[12];
    const float* bout = (const float*)d_in[13];
    float* out = (float*)d_out;

    const int N = in_sizes[0] / 128;
    const int E = in_sizes[2];
    const size_t NPAD = 50048;

    ushort_t* xb    = (ushort_t*)d_ws;              // [N,128] bf16
    ushort_t* hA    = xb + NPAD * 128;
    ushort_t* hB    = hA + NPAD * 128;
    ushort_t* gbuf  = hB + NPAD * 128;
    ushort_t* wcat  = gbuf + NPAD * 128;            // 3*128*256 bf16
    ushort_t* woutb = wcat + 3 * 32768;             // 32*128 bf16
    int* flag       = (int*)(woutb + 4096);
    int* deg        = flag + 1;
    int* rowptr     = deg + N;
    int* bsum       = rowptr + N;
    int* boff       = bsum + 256;
    uint_t* csr     = (uint_t*)(boff + 256);        // E packed entries
    (void)ws_size;

    const int ZB = (N + 255) / 256;                 // 196
    const int WB = (3 * 32768 + 4096 + 255) / 256;  // 400
    const int XB = (N * 32 + 255) / 256;            // 6250
    const int PB = ZB;
    const int gE1 = (E + 255) / 256;                // 3125
    const int gG = (N + 63) / 64;                   // 782
    const int gA = (N + 3) / 4;                     // 1 wave/node
    const int gO = (N + 127) / 128;                 // 391

    SetupArgs sa;
    sa.Wm0 = Wm[0]; sa.Wu0 = Wu[0];
    sa.Wm1 = Wm[1]; sa.Wu1 = Wu[1];
    sa.Wm2 = Wm[2]; sa.Wu2 = Wu[2];
    sa.Wout = Wout; sa.x = x; sa.ei = ei;
    sa.wcat = wcat; sa.woutb = woutb; sa.xb = xb;
    sa.deg = deg; sa.flag = flag;
    sa.N = N; sa.E = E; sa.ZB = ZB; sa.WB = WB; sa.XB = XB;
    setup_kernel<<<ZB + 1 + WB + XB, 256, 0, stream>>>(sa);

    hist_kernel<<<gE1, 256, 0, stream>>>(ei, deg, E, flag);
    scan_partial<<<PB, 256, 0, stream>>>(deg, bsum, N);
    scan_bsum<<<1, 256, 0, stream>>>(bsum, boff, PB);
    scan_write<<<PB, 256, 0, stream>>>(deg, boff, rowptr, N);
    fill_kernel<<<gE1, 256, 0, stream>>>(ei, ew, rowptr, csr, E, flag);

    const ushort_t* hin[3] = {xb, hA, hB};
    ushort_t* hout[3] = {hA, hB, hA};
    for (int l = 0; l < 3; ++l) {
        aggregate_g<<<gA, 256, 0, stream>>>(csr, rowptr, deg, hin[l], gbuf, N);
        fused_gemm<<<gG, 256, 0, stream>>>(gbuf, hin[l], wcat + (size_t)l * 32768,
                                           bu[l], hout[l], N);
    }
    mfma_gemm_out<<<gO, 256, 0, stream>>>(hA, woutb, bout, out, N);
}

// Round 7
// 359.848 us; speedup vs baseline: 1.2755x; 1.0821x over previous
//
#include <hip/hip_runtime.h>
#include <hip/hip_bf16.h>
#include <cstddef>

// ---------------------------------------------------------------------------
// 3-layer MPNN, N=50000, E=800000, D=128, OUT=32.
// R7: CSR build rewritten as 2-phase bucketed counting sort to kill scatter
// line-amplification (R6 evidence: WRITE_SIZE pinned at 64B/edge regardless
// of 4B vs 8B entries -> random-line bound).
//   bin:   edge -> bucket (dst>>7), 8-way partition by blockIdx&7 so each
//          partition's appends stream sequentially (line fills in one L2).
//   bscan: 391-entry scan (small, multi-load, no serial-chain pathology).
//   place: block per bucket: LDS hist -> LDS scan -> LDS image of the
//          bucket's contiguous CSR range -> coalesced flush + deg/rowend.
// Then per layer: g = Sigma w*h[src] (gather);
//   h' = tanh([g|h]@[Wm;Wu]^T+bu) (K=256 MFMA, tanh epilogue);
//   out = h3@Wout^T+bout.
// CSR entry: (src:u16 | w:bf16<<16).
// ---------------------------------------------------------------------------

typedef __attribute__((ext_vector_type(8))) short short8;
typedef __attribute__((ext_vector_type(4))) float f32x4;
typedef unsigned short ushort_t;
typedef unsigned int uint_t;

#define CAPP 512            // staged entries per (bucket,partition)

__device__ inline ushort_t f2bf(float f) {  // round-to-nearest-even
    uint_t u = __float_as_uint(f);
    uint_t r = u + 0x7FFFu + ((u >> 16) & 1u);
    return (ushort_t)(r >> 16);
}
__device__ inline float bf_lo(uint_t u) { return __uint_as_float(u << 16); }
__device__ inline float bf_hi(uint_t u) { return __uint_as_float(u & 0xFFFF0000u); }
__device__ inline uint_t packbf(float a, float b) {
    return (uint_t)f2bf(a) | ((uint_t)f2bf(b) << 16);
}

// flag=1 -> int32 [2][E]; flag=0 -> int64 [2][E] (vectorized low-word read)
__device__ inline int get_dst(const int* __restrict__ ei, int e, int E, int f) {
    if (f) return ei[E + e];
    return ((const int2*)ei)[(size_t)E + e].x;
}
__device__ inline int get_src(const int* __restrict__ ei, int e, int E, int f) {
    if (f) return ei[e];
    return ((const int2*)ei)[e].x;
}

// ---------------------------------------------------------------------------
// Fused setup: zero bucket tails | detect idx layout | bf16 Wcat + Wout |
// x -> bf16.
// ---------------------------------------------------------------------------
struct SetupArgs {
    const float* Wm0; const float* Wu0;
    const float* Wm1; const float* Wu1;
    const float* Wm2; const float* Wu2;
    const float* Wout;
    const float* x; const int* ei;
    ushort_t* wcat;    // 3 * 128*256
    ushort_t* woutb;   // 32*128
    ushort_t* xb;      // N*128
    int* tails;        // NB*8 counters, stride 4 ints (16B anti-contention)
    int* flag;
    int N, E, TI;      // TI = NB*32 total tail ints
    int ZT, WB, XB;
};
__global__ __launch_bounds__(256) void setup_kernel(SetupArgs a) {
    int bx = blockIdx.x, t = threadIdx.x;
    if (bx < a.ZT) {
        int i = bx * 256 + t;
        if (i < a.TI) a.tails[i] = 0;
        return;
    }
    bx -= a.ZT;
    if (bx == 0) {
        __shared__ int any;
        if (t == 0) any = 0;
        __syncthreads();
        int n = a.E < 2048 ? a.E : 2048;
        for (int i = t; i < n; i += 256)
            if (a.ei[2 * i + 1] != 0) any = 1;
        __syncthreads();
        if (t == 0) a.flag[0] = any;
        return;
    }
    bx -= 1;
    if (bx < a.WB) {
        int i = bx * 256 + t;
        if (i < 3 * 32768) {
            int l = i >> 15, rem = i & 32767, r = rem >> 8, k = rem & 255;
            const float* Wm = l == 0 ? a.Wm0 : (l == 1 ? a.Wm1 : a.Wm2);
            const float* Wu = l == 0 ? a.Wu0 : (l == 1 ? a.Wu1 : a.Wu2);
            float v = k < 128 ? Wm[r * 128 + k] : Wu[r * 128 + (k - 128)];
            a.wcat[(size_t)l * 32768 + r * 256 + k] = f2bf(v);
        } else if (i < 3 * 32768 + 4096) {
            int j = i - 3 * 32768;
            a.woutb[j] = f2bf(a.Wout[j]);
        }
        return;
    }
    bx -= a.WB;
    {
        int j = bx * 256 + t;
        if (j < a.N * 32) {
            float4 v = *(const float4*)(a.x + (size_t)j * 4);
            uint2 o;
            o.x = packbf(v.x, v.y);
            o.y = packbf(v.z, v.w);
            *(uint2*)(a.xb + (size_t)j * 4) = o;
        }
    }
}

// ---------------------------------------------------------------------------
// Phase A: bin edges into (bucket = dst>>7, partition = blockIdx&7).
// Appends are sequential per partition -> lines fill before eviction.
// ---------------------------------------------------------------------------
__global__ __launch_bounds__(256) void bin_kernel(
    const int* __restrict__ ei, const float* __restrict__ ew,
    const int* __restrict__ flag, int* __restrict__ tails,
    uint2* __restrict__ staged, int E) {
    int e = blockIdx.x * 256 + threadIdx.x;
    if (e >= E) return;
    int f = flag[0];
    int s = get_src(ei, e, E, f);
    int d = get_dst(ei, e, E, f);
    int bp = (d >> 7) * 8 + (blockIdx.x & 7);
    int slot = atomicAdd(&tails[bp * 4], 1);
    if (slot < CAPP) {
        uint2 v;
        v.x = (uint_t)s | ((uint_t)f2bf(ew[e]) << 16);
        v.y = (uint_t)(d & 127);
        staged[((size_t)bp << 9) + slot] = v;
    }
}

// exclusive scan of per-bucket totals -> csrBase[NB]. NB<=512, one block.
__global__ __launch_bounds__(512) void bucket_scan(
    const int* __restrict__ tails, int* __restrict__ csrBase, int NB) {
    __shared__ int sm[512];
    int t = threadIdx.x;
    int s = 0;
    if (t < NB) {
#pragma unroll
        for (int p = 0; p < 8; ++p) {
            int c = tails[(t * 8 + p) * 4];
            s += c < CAPP ? c : CAPP;
        }
    }
    sm[t] = s;
    __syncthreads();
    for (int o = 1; o < 512; o <<= 1) {
        int v = t >= o ? sm[t - o] : 0;
        __syncthreads();
        sm[t] += v;
        __syncthreads();
    }
    if (t < NB) csrBase[t] = sm[t] - s;
}

// ---------------------------------------------------------------------------
// Phase B: one block per bucket. LDS hist (128 nodes) -> LDS excl scan ->
// place entries in LDS image of the bucket's contiguous CSR range ->
// coalesced flush. Also writes deg[] and rowend[] (coalesced).
// ---------------------------------------------------------------------------
__global__ __launch_bounds__(256) void place_kernel(
    const uint2* __restrict__ staged, const int* __restrict__ tails,
    const int* __restrict__ csrBase, uint_t* __restrict__ csr,
    int* __restrict__ rowend, int* __restrict__ deg, int N) {
    __shared__ int cnt[128], cur[128], excl[128], sm[256], pcnt[8];
    __shared__ uint_t outb[8 * CAPP];
    const int b = blockIdx.x, tid = threadIdx.x;
    const int node0 = b << 7;
    const int base = csrBase[b];
    if (tid < 8) {
        int c = tails[(b * 8 + tid) * 4];
        pcnt[tid] = c < CAPP ? c : CAPP;
    }
    if (tid < 128) cnt[tid] = 0;
    __syncthreads();
    // pass 1: per-node counts
    for (int p = 0; p < 8; ++p) {
        int c = pcnt[p];
        const uint2* sp = staged + ((size_t)(b * 8 + p) << 9);
        for (int i = tid; i < c; i += 256) atomicAdd(&cnt[sp[i].y], 1);
    }
    __syncthreads();
    int c0 = tid < 128 ? cnt[tid] : 0;
    sm[tid] = c0;
    __syncthreads();
    for (int o = 1; o < 256; o <<= 1) {
        int v = tid >= o ? sm[tid - o] : 0;
        __syncthreads();
        sm[tid] += v;
        __syncthreads();
    }
    if (tid < 128) {
        excl[tid] = sm[tid] - c0;
        cur[tid] = 0;
    }
    __syncthreads();
    // pass 2: place into LDS image
    for (int p = 0; p < 8; ++p) {
        int c = pcnt[p];
        const uint2* sp = staged + ((size_t)(b * 8 + p) << 9);
        for (int i = tid; i < c; i += 256) {
            uint2 e = sp[i];
            int pos = excl[e.y] + atomicAdd(&cur[e.y], 1);
            outb[pos] = e.x;
        }
    }
    __syncthreads();
    // coalesced flush of the bucket's contiguous CSR range
    int tot = sm[255];
    for (int i = tid; i < tot; i += 256) csr[base + i] = outb[i];
    if (tid < 128 && node0 + tid < N) {
        deg[node0 + tid] = c0;
        rowend[node0 + tid] = base + excl[tid] + c0;
    }
}

// ---------------------------------------------------------------------------
// Aggregate: g[d] = Sigma_{in(d)} w*h[src]. One 64-lane wave per node.
// lane = e_slot(0..3)*16 + f16(0..15); lane loads 16B (8 bf16 feats).
// 4 row-gathers in flight; shfl_xor(16,32) reduce at end.
// ---------------------------------------------------------------------------
__global__ __launch_bounds__(256) void aggregate_g(
    const uint_t* __restrict__ csr, const int* __restrict__ rowend,
    const int* __restrict__ deg, const ushort_t* __restrict__ h,
    ushort_t* __restrict__ g, int N) {
    int node = (blockIdx.x * 256 + threadIdx.x) >> 6;
    if (node >= N) return;
    int lane = threadIdx.x & 63;
    int e_slot = lane >> 4, f16 = lane & 15;
    int end = rowend[node];
    int beg = end - deg[node];
    float s0 = 0.f, s1 = 0.f, s2 = 0.f, s3 = 0.f;
    float s4 = 0.f, s5 = 0.f, s6 = 0.f, s7 = 0.f;
    for (int j = beg + e_slot; j < end; j += 4) {
        uint_t p = csr[j];
        float w = bf_hi(p);
        uint4 v = *(const uint4*)(h + (size_t)(p & 0xFFFFu) * 128 + f16 * 8);
        s0 += w * bf_lo(v.x); s1 += w * bf_hi(v.x);
        s2 += w * bf_lo(v.y); s3 += w * bf_hi(v.y);
        s4 += w * bf_lo(v.z); s5 += w * bf_hi(v.z);
        s6 += w * bf_lo(v.w); s7 += w * bf_hi(v.w);
    }
    s0 += __shfl_xor(s0, 16, 64); s1 += __shfl_xor(s1, 16, 64);
    s2 += __shfl_xor(s2, 16, 64); s3 += __shfl_xor(s3, 16, 64);
    s4 += __shfl_xor(s4, 16, 64); s5 += __shfl_xor(s5, 16, 64);
    s6 += __shfl_xor(s6, 16, 64); s7 += __shfl_xor(s7, 16, 64);
    s0 += __shfl_xor(s0, 32, 64); s1 += __shfl_xor(s1, 32, 64);
    s2 += __shfl_xor(s2, 32, 64); s3 += __shfl_xor(s3, 32, 64);
    s4 += __shfl_xor(s4, 32, 64); s5 += __shfl_xor(s5, 32, 64);
    s6 += __shfl_xor(s6, 32, 64); s7 += __shfl_xor(s7, 32, 64);
    if (e_slot == 0) {
        uint4 o;
        o.x = packbf(s0, s1);
        o.y = packbf(s2, s3);
        o.z = packbf(s4, s5);
        o.w = packbf(s6, s7);
        *(uint4*)(g + (size_t)node * 128 + f16 * 8) = o;
    }
}

// ---------------------------------------------------------------------------
// Fused layer GEMM: Hout[N,128] = tanh([G|H][N,256] @ Wcat[128,256]^T + bu)
// BM=64, BN=128; LDS chunk layout (lane-contiguous 16B, conflict-free).
// ---------------------------------------------------------------------------
__global__ __launch_bounds__(256) void fused_gemm(
    const ushort_t* __restrict__ G, const ushort_t* __restrict__ H,
    const ushort_t* __restrict__ Wcat, const float* __restrict__ bias,
    ushort_t* __restrict__ Hout, int N) {
    __shared__ short As[64 * 128];    // 16 KB
    __shared__ short Ws[128 * 128];   // 32 KB
    const int tid = threadIdx.x;
    const int row0 = blockIdx.x * 64;
    const int wv = tid >> 6, lane = tid & 63;
    const int rt = wv;

    f32x4 acc[8];
#pragma unroll
    for (int ct = 0; ct < 8; ++ct) acc[ct] = (f32x4){0.f, 0.f, 0.f, 0.f};

#pragma unroll
    for (int chunk = 0; chunk < 2; ++chunk) {
        const ushort_t* A = chunk ? H : G;
        const int kco = chunk * 128;
        if (chunk) __syncthreads();
#pragma unroll
        for (int it = 0; it < 4; ++it) {
            int c = tid + 256 * it;
            int mm = c & 15, q = (c >> 4) & 3, ks = (c >> 6) & 3, rtile = c >> 8;
            int gr = row0 + rtile * 16 + mm;
            short8 v = {0, 0, 0, 0, 0, 0, 0, 0};
            if (gr < N) v = *(const short8*)(A + (size_t)gr * 128 + ks * 32 + q * 8);
            *(short8*)&As[c * 8] = v;
        }
#pragma unroll
        for (int it = 0; it < 8; ++it) {
            int c = tid + 256 * it;
            int mm = c & 15, q = (c >> 4) & 3, ks = (c >> 6) & 3, ct = c >> 8;
            *(short8*)&Ws[c * 8] =
                *(const short8*)(Wcat + (size_t)(ct * 16 + mm) * 256 + kco + ks * 32 + q * 8);
        }
        __syncthreads();
#pragma unroll
        for (int ks = 0; ks < 4; ++ks) {
            short8 a = *(const short8*)&As[((rt * 4 + ks) * 64 + lane) * 8];
#pragma unroll
            for (int ct = 0; ct < 8; ++ct) {
                short8 b = *(const short8*)&Ws[((ct * 4 + ks) * 64 + lane) * 8];
                acc[ct] = __builtin_amdgcn_mfma_f32_16x16x32_bf16(a, b, acc[ct], 0, 0, 0);
            }
        }
    }
    const int colL = lane & 15, rq = lane >> 4;
#pragma unroll
    for (int ct = 0; ct < 8; ++ct) {
        int col = ct * 16 + colL;
        float bv = bias[col];
#pragma unroll
        for (int reg = 0; reg < 4; ++reg) {
            int gr = row0 + rt * 16 + rq * 4 + reg;
            if (gr >= N) continue;
            Hout[(size_t)gr * 128 + col] = f2bf(tanhf(acc[ct][reg] + bv));
        }
    }
}

// out[N,32] = H_bf16[N,128] @ Wout^T + bout (fp32). BM=128.
__global__ __launch_bounds__(256) void mfma_gemm_out(
    const ushort_t* __restrict__ H, const ushort_t* __restrict__ Wb,
    const float* __restrict__ bias, float* __restrict__ C, int N) {
    __shared__ short As[128 * 128];  // 32 KB
    __shared__ short Ws[32 * 128];   // 8 KB
    const int tid = threadIdx.x;
    const int row0 = blockIdx.x * 128;
#pragma unroll
    for (int it = 0; it < 8; ++it) {
        int c = tid + 256 * it;
        int mm = c & 15, q = (c >> 4) & 3, ks = (c >> 6) & 3, rt = c >> 8;
        int gr = row0 + rt * 16 + mm;
        short8 v = {0, 0, 0, 0, 0, 0, 0, 0};
        if (gr < N) v = *(const short8*)(H + (size_t)gr * 128 + ks * 32 + q * 8);
        *(short8*)&As[c * 8] = v;
    }
#pragma unroll
    for (int it = 0; it < 2; ++it) {
        int c = tid + 256 * it;
        int mm = c & 15, q = (c >> 4) & 3, ks = (c >> 6) & 3, ct = c >> 8;
        *(short8*)&Ws[c * 8] =
            *(const short8*)(Wb + (ct * 16 + mm) * 128 + ks * 32 + q * 8);
    }
    __syncthreads();
    const int wv = tid >> 6, lane = tid & 63;
    const int rt0 = wv * 2;
    f32x4 acc[2][2];
#pragma unroll
    for (int r = 0; r < 2; ++r)
#pragma unroll
        for (int c = 0; c < 2; ++c) acc[r][c] = (f32x4){0.f, 0.f, 0.f, 0.f};
#pragma unroll
    for (int ks = 0; ks < 4; ++ks) {
        short8 a0 = *(const short8*)&As[(((rt0 + 0) * 4 + ks) * 64 + lane) * 8];
        short8 a1 = *(const short8*)&As[(((rt0 + 1) * 4 + ks) * 64 + lane) * 8];
#pragma unroll
        for (int ct = 0; ct < 2; ++ct) {
            short8 b = *(const short8*)&Ws[((ct * 4 + ks) * 64 + lane) * 8];
            acc[0][ct] = __builtin_amdgcn_mfma_f32_16x16x32_bf16(a0, b, acc[0][ct], 0, 0, 0);
            acc[1][ct] = __builtin_amdgcn_mfma_f32_16x16x32_bf16(a1, b, acc[1][ct], 0, 0, 0);
        }
    }
    const int colL = lane & 15, rq = lane >> 4;
#pragma unroll
    for (int r = 0; r < 2; ++r)
#pragma unroll
        for (int ct = 0; ct < 2; ++ct) {
            int col = ct * 16 + colL;
            float bv = bias[col];
#pragma unroll
            for (int reg = 0; reg < 4; ++reg) {
                int gr = row0 + (rt0 + r) * 16 + rq * 4 + reg;
                if (gr < N) C[(size_t)gr * 32 + col] = acc[r][ct][reg] + bv;
            }
        }
}

extern "C" void kernel_launch(void* const* d_in, const int* in_sizes, int n_in,
                              void* d_out, int out_size, void* d_ws, size_t ws_size,
                              hipStream_t stream) {
    const float* x   = (const float*)d_in[0];
    const int* ei    = (const int*)d_in[1];
    const float* ew  = (const float*)d_in[2];
    const float* Wm[3] = {(const float*)d_in[3], (const float*)d_in[6], (const float*)d_in[9]};
    const float* Wu[3] = {(const float*)d_in[4], (const float*)d_in[7], (const float*)d_in[10]};
    const float* bu[3] = {(const float*)d_in[5], (const float*)d_in[8], (const float*)d_in[11]};
    const float* Wout = (const float*)d_in[12];
    const float* bout = (const float*)d_in[13];
    float* out = (float*)d_out;

    const int N = in_sizes[0] / 128;
    const int E = in_sizes[2];
    const size_t NPAD = 50048;
    const int NB = (N + 127) / 128;      // 391 buckets
    const int TI = NB * 32;              // tail ints (8 partitions, stride 4)

    ushort_t* xb    = (ushort_t*)d_ws;              // [N,128] bf16
    ushort_t* hA    = xb + NPAD * 128;
    ushort_t* hB    = hA + NPAD * 128;
    ushort_t* gbuf  = hB + NPAD * 128;
    ushort_t* wcat  = gbuf + NPAD * 128;            // 3*128*256 bf16
    ushort_t* woutb = wcat + 3 * 32768;             // 32*128 bf16
    int* flag       = (int*)(woutb + 4096);
    int* tails      = flag + 1;
    int* csrBase    = tails + TI;
    int* rowend     = csrBase + NB + 8;
    int* deg        = rowend + N;
    int* endp       = deg + N;
    uint2* staged   = (uint2*)(((uintptr_t)endp + 7) & ~(uintptr_t)7);
    uint_t* csr     = (uint_t*)(staged + (size_t)NB * 8 * CAPP);
    (void)ws_size;

    const int ZT = (TI + 255) / 256;                // 49
    const int WB = (3 * 32768 + 4096 + 255) / 256;  // 400
    const int XB = (N * 32 + 255) / 256;            // 6250
    const int gE1 = (E + 255) / 256;                // 3125
    const int gG = (N + 63) / 64;                   // 782
    const int gA = (N + 3) / 4;                     // 1 wave/node
    const int gO = (N + 127) / 128;                 // 391

    SetupArgs sa;
    sa.Wm0 = Wm[0]; sa.Wu0 = Wu[0];
    sa.Wm1 = Wm[1]; sa.Wu1 = Wu[1];
    sa.Wm2 = Wm[2]; sa.Wu2 = Wu[2];
    sa.Wout = Wout; sa.x = x; sa.ei = ei;
    sa.wcat = wcat; sa.woutb = woutb; sa.xb = xb;
    sa.tails = tails; sa.flag = flag;
    sa.N = N; sa.E = E; sa.TI = TI;
    sa.ZT = ZT; sa.WB = WB; sa.XB = XB;
    setup_kernel<<<ZT + 1 + WB + XB, 256, 0, stream>>>(sa);

    bin_kernel<<<gE1, 256, 0, stream>>>(ei, ew, flag, tails, staged, E);
    bucket_scan<<<1, 512, 0, stream>>>(tails, csrBase, NB);
    place_kernel<<<NB, 256, 0, stream>>>(staged, tails, csrBase, csr, rowend, deg, N);

    const ushort_t* hin[3] = {xb, hA, hB};
    ushort_t* hout[3] = {hA, hB, hA};
    for (int l = 0; l < 3; ++l) {
        aggregate_g<<<gA, 256, 0, stream>>>(csr, rowend, deg, hin[l], gbuf, N);
        fused_gemm<<<gG, 256, 0, stream>>>(gbuf, hin[l], wcat + (size_t)l * 32768,
                                           bu[l], hout[l], N);
    }
    mfma_gemm_out<<<gO, 256, 0, stream>>>(hA, woutb, bout, out, N);
}

// Round 8
// 345.891 us; speedup vs baseline: 1.3269x; 1.0404x over previous
//
#include <hip/hip_runtime.h>
#include <hip/hip_bf16.h>
#include <cstddef>

// ---------------------------------------------------------------------------
// 3-layer MPNN, N=50000, E=800000, D=128, OUT=32.
// R8: bin partitions by TRUE XCD id (s_getreg HW_REG_XCC_ID) so staged lines
// fill within one XCD's L2 (R7 evidence: 5x write amplification from
// cross-XCD line sharing under blockIdx&7). Tails counters at 64B stride.
// Overflow-retry makes partition choice correctness-free (pure locality).
// Aggregate: 8 edge-slots x 8 feat-lanes, 2x uint4/lane = 2x bytes in
// flight per wave vs R7.
//   g = Sigma_in w*h[src]; h' = tanh([g|h]@[Wm;Wu]^T+bu); out = h3@Wout^T+b.
// CSR entry: (src:u16 | w:bf16<<16).
// ---------------------------------------------------------------------------

typedef __attribute__((ext_vector_type(8))) short short8;
typedef __attribute__((ext_vector_type(4))) float f32x4;
typedef unsigned short ushort_t;
typedef unsigned int uint_t;

#define CAPP 512            // staged entries per (bucket,partition)
#define TSTRIDE 16          // tails counter stride in ints (64B: 1 line each)

__device__ inline ushort_t f2bf(float f) {  // round-to-nearest-even
    uint_t u = __float_as_uint(f);
    uint_t r = u + 0x7FFFu + ((u >> 16) & 1u);
    return (ushort_t)(r >> 16);
}
__device__ inline float bf_lo(uint_t u) { return __uint_as_float(u << 16); }
__device__ inline float bf_hi(uint_t u) { return __uint_as_float(u & 0xFFFF0000u); }
__device__ inline uint_t packbf(float a, float b) {
    return (uint_t)f2bf(a) | ((uint_t)f2bf(b) << 16);
}

// flag=1 -> int32 [2][E]; flag=0 -> int64 [2][E] (vectorized low-word read)
__device__ inline int get_dst(const int* __restrict__ ei, int e, int E, int f) {
    if (f) return ei[E + e];
    return ((const int2*)ei)[(size_t)E + e].x;
}
__device__ inline int get_src(const int* __restrict__ ei, int e, int E, int f) {
    if (f) return ei[e];
    return ((const int2*)ei)[e].x;
}

// ---------------------------------------------------------------------------
// Fused setup: zero bucket tails | detect idx layout | bf16 Wcat + Wout |
// x -> bf16.
// ---------------------------------------------------------------------------
struct SetupArgs {
    const float* Wm0; const float* Wu0;
    const float* Wm1; const float* Wu1;
    const float* Wm2; const float* Wu2;
    const float* Wout;
    const float* x; const int* ei;
    ushort_t* wcat;    // 3 * 128*256
    ushort_t* woutb;   // 32*128
    ushort_t* xb;      // N*128
    int* tails;        // NB*8 counters, stride TSTRIDE ints
    int* flag;
    int N, E, TI;      // TI = NB*8*TSTRIDE total tail ints
    int ZT, WB, XB;
};
__global__ __launch_bounds__(256) void setup_kernel(SetupArgs a) {
    int bx = blockIdx.x, t = threadIdx.x;
    if (bx < a.ZT) {
        int i = bx * 256 + t;
        if (i < a.TI) a.tails[i] = 0;
        return;
    }
    bx -= a.ZT;
    if (bx == 0) {
        __shared__ int any;
        if (t == 0) any = 0;
        __syncthreads();
        int n = a.E < 2048 ? a.E : 2048;
        for (int i = t; i < n; i += 256)
            if (a.ei[2 * i + 1] != 0) any = 1;
        __syncthreads();
        if (t == 0) a.flag[0] = any;
        return;
    }
    bx -= 1;
    if (bx < a.WB) {
        int i = bx * 256 + t;
        if (i < 3 * 32768) {
            int l = i >> 15, rem = i & 32767, r = rem >> 8, k = rem & 255;
            const float* Wm = l == 0 ? a.Wm0 : (l == 1 ? a.Wm1 : a.Wm2);
            const float* Wu = l == 0 ? a.Wu0 : (l == 1 ? a.Wu1 : a.Wu2);
            float v = k < 128 ? Wm[r * 128 + k] : Wu[r * 128 + (k - 128)];
            a.wcat[(size_t)l * 32768 + r * 256 + k] = f2bf(v);
        } else if (i < 3 * 32768 + 4096) {
            int j = i - 3 * 32768;
            a.woutb[j] = f2bf(a.Wout[j]);
        }
        return;
    }
    bx -= a.WB;
    {
        int j = bx * 256 + t;
        if (j < a.N * 32) {
            float4 v = *(const float4*)(a.x + (size_t)j * 4);
            uint2 o;
            o.x = packbf(v.x, v.y);
            o.y = packbf(v.z, v.w);
            *(uint2*)(a.xb + (size_t)j * 4) = o;
        }
    }
}

// ---------------------------------------------------------------------------
// Phase A: bin edges into (bucket = dst>>7, partition = hardware XCD id).
// All appends to a (bucket,xcd) region come from ONE XCD's L2 -> lines fill
// locally. Partition is a pure locality hint: on overflow (or a bogus
// s_getreg value) the retry loop walks partitions, so no edge is dropped
// (8*CAPP=4096 >= max bucket size ~2.3k).
// ---------------------------------------------------------------------------
__global__ __launch_bounds__(256) void bin_kernel(
    const int* __restrict__ ei, const float* __restrict__ ew,
    const int* __restrict__ flag, int* __restrict__ tails,
    uint2* __restrict__ staged, int E) {
    int e = blockIdx.x * 256 + threadIdx.x;
    if (e >= E) return;
    // HW_REG_XCC_ID (id=20), offset 0, size 4: simm16 = (4-1)<<11 | 0<<6 | 20
    int xcd = __builtin_amdgcn_s_getreg((3 << 11) | 20) & 7;
    int f = flag[0];
    int s = get_src(ei, e, E, f);
    int d = get_dst(ei, e, E, f);
    uint2 v;
    v.x = (uint_t)s | ((uint_t)f2bf(ew[e]) << 16);
    v.y = (uint_t)(d & 127);
    int b = d >> 7;
    int p = xcd;
#pragma unroll 1
    for (int t = 0; t < 8; ++t) {
        int bp = b * 8 + p;
        int slot = atomicAdd(&tails[bp * TSTRIDE], 1);
        if (slot < CAPP) {
            staged[((size_t)bp << 9) + slot] = v;
            break;
        }
        p = (p + 1) & 7;
    }
}

// exclusive scan of per-bucket totals -> csrBase[NB]. NB<=512, one block.
__global__ __launch_bounds__(512) void bucket_scan(
    const int* __restrict__ tails, int* __restrict__ csrBase, int NB) {
    __shared__ int sm[512];
    int t = threadIdx.x;
    int s = 0;
    if (t < NB) {
#pragma unroll
        for (int p = 0; p < 8; ++p) {
            int c = tails[(t * 8 + p) * TSTRIDE];
            s += c < CAPP ? c : CAPP;
        }
    }
    sm[t] = s;
    __syncthreads();
    for (int o = 1; o < 512; o <<= 1) {
        int v = t >= o ? sm[t - o] : 0;
        __syncthreads();
        sm[t] += v;
        __syncthreads();
    }
    if (t < NB) csrBase[t] = sm[t] - s;
}

// ---------------------------------------------------------------------------
// Phase B: one block per bucket. LDS hist (128 nodes) -> LDS excl scan ->
// place into LDS image of the bucket's contiguous CSR range -> coalesced
// flush. Writes deg[] and rowend[] (coalesced).
// ---------------------------------------------------------------------------
__global__ __launch_bounds__(256) void place_kernel(
    const uint2* __restrict__ staged, const int* __restrict__ tails,
    const int* __restrict__ csrBase, uint_t* __restrict__ csr,
    int* __restrict__ rowend, int* __restrict__ deg, int N) {
    __shared__ int cnt[128], cur[128], excl[128], sm[256], pcnt[8];
    __shared__ uint_t outb[8 * CAPP];
    const int b = blockIdx.x, tid = threadIdx.x;
    const int node0 = b << 7;
    const int base = csrBase[b];
    if (tid < 8) {
        int c = tails[(b * 8 + tid) * TSTRIDE];
        pcnt[tid] = c < CAPP ? c : CAPP;
    }
    if (tid < 128) cnt[tid] = 0;
    __syncthreads();
    for (int p = 0; p < 8; ++p) {
        int c = pcnt[p];
        const uint2* sp = staged + ((size_t)(b * 8 + p) << 9);
        for (int i = tid; i < c; i += 256) atomicAdd(&cnt[sp[i].y], 1);
    }
    __syncthreads();
    int c0 = tid < 128 ? cnt[tid] : 0;
    sm[tid] = c0;
    __syncthreads();
    for (int o = 1; o < 256; o <<= 1) {
        int v = tid >= o ? sm[tid - o] : 0;
        __syncthreads();
        sm[tid] += v;
        __syncthreads();
    }
    if (tid < 128) {
        excl[tid] = sm[tid] - c0;
        cur[tid] = 0;
    }
    __syncthreads();
    for (int p = 0; p < 8; ++p) {
        int c = pcnt[p];
        const uint2* sp = staged + ((size_t)(b * 8 + p) << 9);
        for (int i = tid; i < c; i += 256) {
            uint2 e = sp[i];
            int pos = excl[e.y] + atomicAdd(&cur[e.y], 1);
            outb[pos] = e.x;
        }
    }
    __syncthreads();
    int tot = sm[255];
    for (int i = tid; i < tot; i += 256) csr[base + i] = outb[i];
    if (tid < 128 && node0 + tid < N) {
        deg[node0 + tid] = c0;
        rowend[node0 + tid] = base + excl[tid] + c0;
    }
}

// ---------------------------------------------------------------------------
// Aggregate: g[d] = Sigma_{in(d)} w*h[src]. One 64-lane wave per node.
// lane = e_slot(0..7)*8 + f8(0..7); lane owns 16 feats via 2x uint4 loads.
// 8 rows (2 KB) in flight per wave-iteration; 3-step shfl_xor reduction.
// ---------------------------------------------------------------------------
__global__ __launch_bounds__(256) void aggregate_g(
    const uint_t* __restrict__ csr, const int* __restrict__ rowend,
    const int* __restrict__ deg, const ushort_t* __restrict__ h,
    ushort_t* __restrict__ g, int N) {
    int node = (blockIdx.x * 256 + threadIdx.x) >> 6;
    if (node >= N) return;
    int lane = threadIdx.x & 63;
    int slot = lane >> 3, f8 = lane & 7;
    int end = rowend[node];
    int beg = end - deg[node];
    float s[16];
#pragma unroll
    for (int k = 0; k < 16; ++k) s[k] = 0.f;
    for (int j = beg + slot; j < end; j += 8) {
        uint_t p = csr[j];
        float w = bf_hi(p);
        const ushort_t* row = h + (size_t)(p & 0xFFFFu) * 128 + f8 * 16;
        uint4 v0 = *(const uint4*)(row);
        uint4 v1 = *(const uint4*)(row + 8);
        s[0] += w * bf_lo(v0.x);  s[1] += w * bf_hi(v0.x);
        s[2] += w * bf_lo(v0.y);  s[3] += w * bf_hi(v0.y);
        s[4] += w * bf_lo(v0.z);  s[5] += w * bf_hi(v0.z);
        s[6] += w * bf_lo(v0.w);  s[7] += w * bf_hi(v0.w);
        s[8] += w * bf_lo(v1.x);  s[9] += w * bf_hi(v1.x);
        s[10] += w * bf_lo(v1.y); s[11] += w * bf_hi(v1.y);
        s[12] += w * bf_lo(v1.z); s[13] += w * bf_hi(v1.z);
        s[14] += w * bf_lo(v1.w); s[15] += w * bf_hi(v1.w);
    }
#pragma unroll
    for (int k = 0; k < 16; ++k) s[k] += __shfl_xor(s[k], 8, 64);
#pragma unroll
    for (int k = 0; k < 16; ++k) s[k] += __shfl_xor(s[k], 16, 64);
#pragma unroll
    for (int k = 0; k < 16; ++k) s[k] += __shfl_xor(s[k], 32, 64);
    if (slot == 0) {
        uint4 o0, o1;
        o0.x = packbf(s[0], s[1]);   o0.y = packbf(s[2], s[3]);
        o0.z = packbf(s[4], s[5]);   o0.w = packbf(s[6], s[7]);
        o1.x = packbf(s[8], s[9]);   o1.y = packbf(s[10], s[11]);
        o1.z = packbf(s[12], s[13]); o1.w = packbf(s[14], s[15]);
        ushort_t* gp = g + (size_t)node * 128 + f8 * 16;
        *(uint4*)(gp) = o0;
        *(uint4*)(gp + 8) = o1;
    }
}

// ---------------------------------------------------------------------------
// Fused layer GEMM: Hout[N,128] = tanh([G|H][N,256] @ Wcat[128,256]^T + bu)
// BM=64, BN=128; LDS chunk layout (lane-contiguous 16B, conflict-free).
// ---------------------------------------------------------------------------
__global__ __launch_bounds__(256) void fused_gemm(
    const ushort_t* __restrict__ G, const ushort_t* __restrict__ H,
    const ushort_t* __restrict__ Wcat, const float* __restrict__ bias,
    ushort_t* __restrict__ Hout, int N) {
    __shared__ short As[64 * 128];    // 16 KB
    __shared__ short Ws[128 * 128];   // 32 KB
    const int tid = threadIdx.x;
    const int row0 = blockIdx.x * 64;
    const int wv = tid >> 6, lane = tid & 63;
    const int rt = wv;

    f32x4 acc[8];
#pragma unroll
    for (int ct = 0; ct < 8; ++ct) acc[ct] = (f32x4){0.f, 0.f, 0.f, 0.f};

#pragma unroll
    for (int chunk = 0; chunk < 2; ++chunk) {
        const ushort_t* A = chunk ? H : G;
        const int kco = chunk * 128;
        if (chunk) __syncthreads();
#pragma unroll
        for (int it = 0; it < 4; ++it) {
            int c = tid + 256 * it;
            int mm = c & 15, q = (c >> 4) & 3, ks = (c >> 6) & 3, rtile = c >> 8;
            int gr = row0 + rtile * 16 + mm;
            short8 v = {0, 0, 0, 0, 0, 0, 0, 0};
            if (gr < N) v = *(const short8*)(A + (size_t)gr * 128 + ks * 32 + q * 8);
            *(short8*)&As[c * 8] = v;
        }
#pragma unroll
        for (int it = 0; it < 8; ++it) {
            int c = tid + 256 * it;
            int mm = c & 15, q = (c >> 4) & 3, ks = (c >> 6) & 3, ct = c >> 8;
            *(short8*)&Ws[c * 8] =
                *(const short8*)(Wcat + (size_t)(ct * 16 + mm) * 256 + kco + ks * 32 + q * 8);
        }
        __syncthreads();
#pragma unroll
        for (int ks = 0; ks < 4; ++ks) {
            short8 a = *(const short8*)&As[((rt * 4 + ks) * 64 + lane) * 8];
#pragma unroll
            for (int ct = 0; ct < 8; ++ct) {
                short8 b = *(const short8*)&Ws[((ct * 4 + ks) * 64 + lane) * 8];
                acc[ct] = __builtin_amdgcn_mfma_f32_16x16x32_bf16(a, b, acc[ct], 0, 0, 0);
            }
        }
    }
    const int colL = lane & 15, rq = lane >> 4;
#pragma unroll
    for (int ct = 0; ct < 8; ++ct) {
        int col = ct * 16 + colL;
        float bv = bias[col];
#pragma unroll
        for (int reg = 0; reg < 4; ++reg) {
            int gr = row0 + rt * 16 + rq * 4 + reg;
            if (gr >= N) continue;
            Hout[(size_t)gr * 128 + col] = f2bf(tanhf(acc[ct][reg] + bv));
        }
    }
}

// out[N,32] = H_bf16[N,128] @ Wout^T + bout (fp32). BM=128.
__global__ __launch_bounds__(256) void mfma_gemm_out(
    const ushort_t* __restrict__ H, const ushort_t* __restrict__ Wb,
    const float* __restrict__ bias, float* __restrict__ C, int N) {
    __shared__ short As[128 * 128];  // 32 KB
    __shared__ short Ws[32 * 128];   // 8 KB
    const int tid = threadIdx.x;
    const int row0 = blockIdx.x * 128;
#pragma unroll
    for (int it = 0; it < 8; ++it) {
        int c = tid + 256 * it;
        int mm = c & 15, q = (c >> 4) & 3, ks = (c >> 6) & 3, rt = c >> 8;
        int gr = row0 + rt * 16 + mm;
        short8 v = {0, 0, 0, 0, 0, 0, 0, 0};
        if (gr < N) v = *(const short8*)(H + (size_t)gr * 128 + ks * 32 + q * 8);
        *(short8*)&As[c * 8] = v;
    }
#pragma unroll
    for (int it = 0; it < 2; ++it) {
        int c = tid + 256 * it;
        int mm = c & 15, q = (c >> 4) & 3, ks = (c >> 6) & 3, ct = c >> 8;
        *(short8*)&Ws[c * 8] =
            *(const short8*)(Wb + (ct * 16 + mm) * 128 + ks * 32 + q * 8);
    }
    __syncthreads();
    const int wv = tid >> 6, lane = tid & 63;
    const int rt0 = wv * 2;
    f32x4 acc[2][2];
#pragma unroll
    for (int r = 0; r < 2; ++r)
#pragma unroll
        for (int c = 0; c < 2; ++c) acc[r][c] = (f32x4){0.f, 0.f, 0.f, 0.f};
#pragma unroll
    for (int ks = 0; ks < 4; ++ks) {
        short8 a0 = *(const short8*)&As[(((rt0 + 0) * 4 + ks) * 64 + lane) * 8];
        short8 a1 = *(const short8*)&As[(((rt0 + 1) * 4 + ks) * 64 + lane) * 8];
#pragma unroll
        for (int ct = 0; ct < 2; ++ct) {
            short8 b = *(const short8*)&Ws[((ct * 4 + ks) * 64 + lane) * 8];
            acc[0][ct] = __builtin_amdgcn_mfma_f32_16x16x32_bf16(a0, b, acc[0][ct], 0, 0, 0);
            acc[1][ct] = __builtin_amdgcn_mfma_f32_16x16x32_bf16(a1, b, acc[1][ct], 0, 0, 0);
        }
    }
    const int colL = lane & 15, rq = lane >> 4;
#pragma unroll
    for (int r = 0; r < 2; ++r)
#pragma unroll
        for (int ct = 0; ct < 2; ++ct) {
            int col = ct * 16 + colL;
            float bv = bias[col];
#pragma unroll
            for (int reg = 0; reg < 4; ++reg) {
                int gr = row0 + (rt0 + r) * 16 + rq * 4 + reg;
                if (gr < N) C[(size_t)gr * 32 + col] = acc[r][ct][reg] + bv;
            }
        }
}

extern "C" void kernel_launch(void* const* d_in, const int* in_sizes, int n_in,
                              void* d_out, int out_size, void* d_ws, size_t ws_size,
                              hipStream_t stream) {
    const float* x   = (const float*)d_in[0];
    const int* ei    = (const int*)d_in[1];
    const float* ew  = (const float*)d_in[2];
    const float* Wm[3] = {(const float*)d_in[3], (const float*)d_in[6], (const float*)d_in[9]};
    const float* Wu[3] = {(const float*)d_in[4], (const float*)d_in[7], (const float*)d_in[10]};
    const float* bu[3] = {(const float*)d_in[5], (const float*)d_in[8], (const float*)d_in[11]};
    const float* Wout = (const float*)d_in[12];
    const float* bout = (const float*)d_in[13];
    float* out = (float*)d_out;

    const int N = in_sizes[0] / 128;
    const int E = in_sizes[2];
    const size_t NPAD = 50048;
    const int NB = (N + 127) / 128;      // 391 buckets
    const int TI = NB * 8 * TSTRIDE;     // tail ints

    ushort_t* xb    = (ushort_t*)d_ws;              // [N,128] bf16
    ushort_t* hA    = xb + NPAD * 128;
    ushort_t* hB    = hA + NPAD * 128;
    ushort_t* gbuf  = hB + NPAD * 128;
    ushort_t* wcat  = gbuf + NPAD * 128;            // 3*128*256 bf16
    ushort_t* woutb = wcat + 3 * 32768;             // 32*128 bf16
    int* flag       = (int*)(woutb + 4096);
    int* tails      = flag + 1;
    int* csrBase    = tails + TI;
    int* rowend     = csrBase + NB + 8;
    int* deg        = rowend + N;
    int* endp       = deg + N;
    uint2* staged   = (uint2*)(((uintptr_t)endp + 7) & ~(uintptr_t)7);
    uint_t* csr     = (uint_t*)(staged + (size_t)NB * 8 * CAPP);
    (void)ws_size;

    const int ZT = (TI + 255) / 256;                // 196
    const int WB = (3 * 32768 + 4096 + 255) / 256;  // 400
    const int XB = (N * 32 + 255) / 256;            // 6250
    const int gE1 = (E + 255) / 256;                // 3125
    const int gG = (N + 63) / 64;                   // 782
    const int gA = (N + 3) / 4;                     // 1 wave/node
    const int gO = (N + 127) / 128;                 // 391

    SetupArgs sa;
    sa.Wm0 = Wm[0]; sa.Wu0 = Wu[0];
    sa.Wm1 = Wm[1]; sa.Wu1 = Wu[1];
    sa.Wm2 = Wm[2]; sa.Wu2 = Wu[2];
    sa.Wout = Wout; sa.x = x; sa.ei = ei;
    sa.wcat = wcat; sa.woutb = woutb; sa.xb = xb;
    sa.tails = tails; sa.flag = flag;
    sa.N = N; sa.E = E; sa.TI = TI;
    sa.ZT = ZT; sa.WB = WB; sa.XB = XB;
    setup_kernel<<<ZT + 1 + WB + XB, 256, 0, stream>>>(sa);

    bin_kernel<<<gE1, 256, 0, stream>>>(ei, ew, flag, tails, staged, E);
    bucket_scan<<<1, 512, 0, stream>>>(tails, csrBase, NB);
    place_kernel<<<NB, 256, 0, stream>>>(staged, tails, csrBase, csr, rowend, deg, N);

    const ushort_t* hin[3] = {xb, hA, hB};
    ushort_t* hout[3] = {hA, hB, hA};
    for (int l = 0; l < 3; ++l) {
        aggregate_g<<<gA, 256, 0, stream>>>(csr, rowend, deg, hin[l], gbuf, N);
        fused_gemm<<<gG, 256, 0, stream>>>(gbuf, hin[l], wcat + (size_t)l * 32768,
                                           bu[l], hout[l], N);
    }
    mfma_gemm_out<<<gO, 256, 0, stream>>>(hA, woutb, bout, out, N);
}